// Round 6
// baseline (217.999 us; speedup 1.0000x reference)
//
#include <hip/hip_runtime.h>

#define BB 16
#define HH 512
#define WW 512
#define HWP (HH*WW)
#define NMAP ((size_t)BB*HWP)

struct __align__(16) V4 { float x, y, z, w; };
__device__ __forceinline__ V4 v4(float a, float b, float c, float d) { V4 r; r.x=a; r.y=b; r.z=c; r.w=d; return r; }
__device__ __forceinline__ V4 v4z() { return v4(0.f,0.f,0.f,0.f); }
__device__ __forceinline__ V4 vadd(V4 a, V4 b) { return v4(a.x+b.x, a.y+b.y, a.z+b.z, a.w+b.w); }
__device__ __forceinline__ V4 vsub(V4 a, V4 b) { return v4(a.x-b.x, a.y-b.y, a.z-b.z, a.w-b.w); }
__device__ __forceinline__ V4 shflV4(V4 v, int sl) {
    V4 r;
    r.x = __shfl(v.x, sl, 64);
    r.y = __shfl(v.y, sl, 64);
    r.z = __shfl(v.z, sl, 64);
    r.w = __shfl(v.w, sl, 64);
    return r;
}

// ---------------------------------------------------------------------------
// Barrier-free guided-filter stage. Each WAVE independently owns a 128-col
// tile (2 cols/lane); horizontal windows resolve in-wave via __shfl
// (pair-sum p = e0+e1; window = (2PH+1) pair fetches + 2 edge singles).
// Validity chain (M = PH+1 = (P+1)/2):
//   A valid on lanes [M, 63-M]  (its shuffles reach lanes [l-M, l+M])
//   emit valid on lanes [2M, 63-2M]  (its ca-window reaches [l-M, l+M])
//   => STRIDE = 128 - 8M emitted cols/tile, c0 = o0 - 4M + 2*lane.
// A is zero outside image COLS (cok guard) and ROWS — matches reference's
// clamped box which never sums nonexistent A. Vertical = running sums +
// static-indexed register rings, fully unrolled. No LDS, no __syncthreads.
// MODE 1: in = x (s,q inline)  MODE 2: in = (s,q) map  MODE 3: + epilogue.
// ---------------------------------------------------------------------------
template <int P, int CH, int MODE>
__global__ __launch_bounds__(256, (P == 7) ? 3 : 4)
void stage(const float* __restrict__ xin, const float2* __restrict__ sqin,
           float2* __restrict__ abo, float2* __restrict__ sqo,
           const float2* __restrict__ abp1, const float2* __restrict__ abp2,
           const float* __restrict__ wt, float* __restrict__ outp, float eps)
{
    constexpr int PH  = (P - 1) / 2;
    constexpr int M   = PH + 1;                       // (P+1)/2
    constexpr int RD  = 2*P + 1;
    constexpr int STRIDE = 128 - 8*M;                 // valid out cols / tile
    constexpr int NT  = (WW + STRIDE - 1) / STRIDE;   // tiles per row
    constexpr int NST = HH / CH;                      // strips
    constexpr int NIT = CH + 2*P + 1;
    constexpr int NB  = (BB * NT * NST) / 4;          // blocks (4 waves each)

    const int lane = threadIdx.x & 63;
    const int bx   = blockIdx.x;
    const int bid  = (bx & 7) * (NB / 8) + (bx >> 3); // XCD-chunked swizzle
    const int wid  = bid * 4 + (threadIdx.x >> 6);
    const int st   = wid % NST;                       // consecutive wid = consecutive strips
    const int ti   = (wid / NST) % NT;
    const int b    = wid / (NST * NT);
    const int h0   = st * CH;
    const int o0   = ti * STRIDE;
    const int c0   = o0 - 4*M + 2*lane;               // even; c1 = c0+1

    const size_t mb_ = (size_t)b * HWP;
    const float*  xb  = (MODE != 2) ? (xin + (size_t)b * 3 * HWP) : nullptr;
    const float2* sqb = (MODE != 1) ? (sqin + mb_) : nullptr;

    const bool cok = (unsigned)c0 < (unsigned)WW;     // pair all-in (c0 even)
    const bool eok = cok && (c0 >= o0) && (c0 < o0 + STRIDE);

    auto cwf = [&](int c) -> float {
        int lo = c - P < 0 ? 0 : c - P;
        int hi = c + P > WW-1 ? WW-1 : c + P;
        int n  = hi - lo + 1;
        return (float)(n < 1 ? 1 : n);
    };
    const float cw0 = cwf(c0), cw1 = cwf(c0 + 1);

    auto loadrow = [&](int rr) -> V4 {                // (s0,q0,s1,q1) at row rr
        if (!cok || (unsigned)rr >= (unsigned)HH) return v4z();
        if constexpr (MODE == 1) {
            size_t o = (size_t)rr * WW + c0;
            float2 a0 = *(const float2*)(xb + o);
            float2 a1 = *(const float2*)(xb + o + HWP);
            float2 a2 = *(const float2*)(xb + o + 2*HWP);
            return v4(a0.x+a1.x+a2.x, a0.x*a0.x + a1.x*a1.x + a2.x*a2.x,
                      a0.y+a1.y+a2.y, a0.y*a0.y + a1.y*a1.y + a2.y*a2.y);
        } else {
            float4 v = *((const float4*)(sqb + (size_t)rr * WW + c0));
            return v4(v.x, v.y, v.z, v.w);
        }
    };

    V4 csv = v4z(), cav = v4z(), prevOut = v4z();
    V4 rgv[RD];
#pragma unroll
    for (int i = 0; i < RD; ++i) rgv[i] = v4z();

    // prime cs: rows [h0-2P, h0] (centered on first A-row h0-P)
#pragma unroll
    for (int d = 0; d <= 2*P; ++d) csv = vadd(csv, loadrow(h0 - 2*P + d));

#pragma unroll
    for (int j = 0; j < NIT; ++j) {
        const int r = h0 - P + j;                     // current A-row
        const int h = r - P - 1;                      // emit row this phase

        // advance-row loads (consumed at phase end)
        V4 inv = v4z(), outv = v4z();
        if (j < NIT - 1) { inv = loadrow(r + 1 + P); outv = loadrow(r - P); }

        // emit-input prefetch (MODE 3)
        float2 q1a = make_float2(0,0), q1b = q1a, q2a = q1a, q2b = q1a;
        float2 xe0 = q1a, xe1 = q1a, xe2 = q1a;
        if constexpr (MODE == 3) {
            if (j >= 2*P + 1 && eok) {
                size_t o = mb_ + (size_t)h * WW + c0;
                q1a = abp1[o]; q1b = abp1[o + 1];
                q2a = abp2[o]; q2b = abp2[o + 1];
                size_t xo = (size_t)h * WW + c0;
                xe0 = *(const float2*)(xb + xo);
                xe1 = *(const float2*)(xb + xo + HWP);
                xe2 = *(const float2*)(xb + xo + 2*HWP);
            }
        }

        // in-register horizontal exchange (no barrier)
        V4 e0 = v4(csv.x, csv.y, cav.x, cav.y);
        V4 e1 = v4(csv.z, csv.w, cav.z, cav.w);
        V4 p  = vadd(e0, e1);
        V4 S  = p;
#pragma unroll
        for (int i = 1; i <= PH; ++i)
            S = vadd(S, vadd(shflV4(p, lane - i), shflV4(p, lane + i)));
        V4 W0 = vadd(S, shflV4(e1, lane - M));        // + col c0-P (odd single)
        V4 W1 = vadd(S, shflV4(e0, lane + M));        // + col c1+P (even single)

        if (j >= 2*P + 1) {
            if constexpr (MODE != 3) {
                if (eok) {
                    size_t o = mb_ + (size_t)h * WW + c0;
                    abo[o]     = make_float2(W0.z, W0.w);
                    abo[o + 1] = make_float2(W1.z, W1.w);
                    float mA0 = 3.f*W0.z, mb0 = 3.f*W0.w;
                    float mA1 = 3.f*W1.z, mb1 = 3.f*W1.w;
                    // prevOut = (s,q) of row h (loaded as outv last phase)
                    sqo[o]     = make_float2(mA0*prevOut.x + 3.f*mb0,
                        mA0*mA0*prevOut.y + 2.f*mA0*mb0*prevOut.x + 3.f*mb0*mb0);
                    sqo[o + 1] = make_float2(mA1*prevOut.z + 3.f*mb1,
                        mA1*mA1*prevOut.w + 2.f*mA1*mb1*prevOut.z + 3.f*mb1*mb1);
                }
            } else {
                if (eok) {
                    float a3  = 3.f*W0.z, b3  = 3.f*W0.w;
                    float a3c = 3.f*W1.z, b3c = 3.f*W1.w;
                    float r0[3], r1[3];
#pragma unroll
                    for (int c = 0; c < 2; ++c) {
                        float P1 = 3.f * (c ? q1b.x : q1a.x), Q1 = 3.f * (c ? q1b.y : q1a.y);
                        float a2 = 3.f * (c ? q2b.x : q2a.x), b2 = 3.f * (c ? q2b.y : q2a.y);
                        float a3v = c ? a3c : a3,             b3v = c ? b3c : b3;
                        float P2 = a2 * P1,  Q2 = a2 * Q1 + b2;
                        float P3 = a3v * P2, Q3 = a3v * Q2 + b3v;
                        float al[3] = {1.f - P1, P1 - P2, P2 - P3};
                        float be[3] = {-Q1,      Q1 - Q2, Q2 - Q3};
                        float x0 = c ? xe0.y : xe0.x;
                        float x1 = c ? xe1.y : xe1.x;
                        float x2 = c ? xe2.y : xe2.x;
                        float* rr_ = c ? r1 : r0;
#pragma unroll
                        for (int oc = 0; oc < 3; ++oc) {
                            float acc = 0.f;
#pragma unroll
                            for (int gg = 0; gg < 3; ++gg) {
                                float wa = wt[oc*9 + gg*3 + 0];
                                float wb = wt[oc*9 + gg*3 + 1];
                                float wc = wt[oc*9 + gg*3 + 2];
                                acc += al[gg] * (wa*x0 + wb*x1 + wc*x2)
                                     + be[gg] * (wa + wb + wc);
                            }
                            rr_[oc] = acc;
                        }
                    }
                    float* ob = outp + (size_t)b * 3 * HWP + (size_t)h * WW + c0;
#pragma unroll
                    for (int oc = 0; oc < 3; ++oc)
                        *((float2*)(ob + (size_t)oc * HWP)) = make_float2(r0[oc], r1[oc]);
                }
            }
        }

        if (j < NIT - 1) {
            // A(r), b(r): zero outside image rows AND cols (reference's box
            // never sums A beyond the image; cok guard enforces that here)
            V4 Av = v4z();
            if (cok && (unsigned)r < (unsigned)HH) {
                int lo = r - P < 0 ? 0 : r - P;
                int hi = r + P > HH-1 ? HH-1 : r + P;
                float chh = (float)(hi - lo + 1);
                float rn0 = 1.f / (3.f * chh * cw0);
                float rn1 = 1.f / (3.f * chh * cw1);
                float m0 = W0.x * rn0,         m1 = W1.x * rn1;
                float v0 = W0.y * rn0 - m0*m0, v1 = W1.y * rn1 - m1*m1;
                float a0 = v0 / (v0 + eps),    a1 = v1 / (v1 + eps);
                Av = v4(a0, m0 * (1.f - a0), a1, m1 * (1.f - a1));
            }
            const int ri = j % RD;                     // static under unroll
            cav = vadd(cav, vsub(Av, rgv[ri]));
            rgv[ri] = Av;
            csv = vadd(csv, vsub(inv, outv));
            prevOut = outv;
        }
    }
}

extern "C" void kernel_launch(void* const* d_in, const int* in_sizes, int n_in,
                              void* d_out, int out_size, void* d_ws, size_t ws_size,
                              hipStream_t stream) {
    (void)in_sizes; (void)n_in; (void)out_size; (void)ws_size;
    const float* x  = (const float*)d_in[0];
    const float* w1 = (const float*)d_in[1];
    float* out = (float*)d_out;

    float2* sq1 = (float2*)d_ws;          // F1 moments
    float2* sq2 = sq1 + NMAP;             // F2 moments
    float2* ab1 = sq2 + NMAP;             // raw (boxA, boxB) of stage 1
    float2* ab2 = ab1 + NMAP;             // raw (boxA, boxB) of stage 2

    dim3 bl(256);
    // waves = BB * NT * (HH/CH); blocks = waves/4
    // stage 1: P=1 -> STRIDE=120, NT=5 -> 2560 waves -> 640 blocks
    stage<1,16,1><<<dim3(640), bl, 0, stream>>>(x, nullptr, ab1, sq1,
                                        nullptr, nullptr, nullptr, nullptr, 0.16f);
    // stage 2: P=3 -> STRIDE=112, NT=5 -> 640 blocks
    stage<3,16,2><<<dim3(640), bl, 0, stream>>>(nullptr, sq1, ab2, sq2,
                                        nullptr, nullptr, nullptr, nullptr, 0.04f);
    // stage 3: P=7 -> STRIDE=96, NT=6 -> 3072 waves -> 768 blocks
    stage<7,16,3><<<dim3(768), bl, 0, stream>>>(x, sq2, nullptr, nullptr,
                                        ab1, ab2, w1, out, 0.01f);
}